// Round 11
// baseline (192.754 us; speedup 1.0000x reference)
//
#include <hip/hip_runtime.h>

#define HW 512
#define PADR 5
#define ROWS 16
#define SEGS 32          // 512/ROWS

typedef _Float16 h2 __attribute__((ext_vector_type(2)));

// DPP wave shifts: pure VALU. bound_ctrl=true zeros invalid lanes; edge lanes
// are overridden by selects below.
__device__ __forceinline__ float dpp_up1(float x) {   // lane i <- lane i-1
    return __int_as_float(__builtin_amdgcn_update_dpp(
        0, __float_as_int(x), 0x138 /*wave_shr:1*/, 0xf, 0xf, true));
}
__device__ __forceinline__ float dpp_dn1(float x) {   // lane i <- lane i+1
    return __int_as_float(__builtin_amdgcn_update_dpp(
        0, __float_as_int(x), 0x130 /*wave_shl:1*/, 0xf, 0xf, true));
}

__global__ __launch_bounds__(128)
void std_loss_kernel(const float* __restrict__ pred,
                     const float* __restrict__ targ,
                     float* __restrict__ out, float invN)
{
    const int tid   = threadIdx.x;
    const int lane  = tid & 63;
    const int halfu = __builtin_amdgcn_readfirstlane(tid >> 6);  // 0|1, SGPR
    const int bid = blockIdx.x;
    const int img = bid / SEGS;
    const int seg = bid - img * SEGS;

    const float* T = targ + (size_t)img * (HW*HW);
    const float* P = pred + (size_t)img * (HW*HW);

    const int c0 = halfu * 256 + lane * 4;   // 4 owned columns
    const int y0 = seg * ROWS;

    // halo[parity][src_half][12]: src 0 exports cols 252-255 (vs,vq) + col 251;
    // src 1 exports cols 256-259 (vs,vq) + col 260. 12-float pad for 16B align.
    __shared__ float halo[2][2][12];
    __shared__ float wsum[2];

    // ---- 11-row fp16 FIFO + running vertical sums for 4 cols ----
    h2 fifo[11][2];
    float vs[4], vq[4];
    vs[0]=vs[1]=vs[2]=vs[3]=0.f;
    vq[0]=vq[1]=vq[2]=vq[3]=0.f;
    #pragma unroll
    for (int j = 0; j < 11; ++j) {
        int ry = min(max(y0 - PADR + j, 0), HW - 1);
        float4 t = *(const float4*)(T + ry*HW + c0);
        h2 lo, hi;
        lo.x=(_Float16)t.x; lo.y=(_Float16)t.y;
        hi.x=(_Float16)t.z; hi.y=(_Float16)t.w;
        fifo[j][0]=lo; fifo[j][1]=hi;
        float q0=(float)lo.x, q1=(float)lo.y, q2=(float)hi.x, q3=(float)hi.y;
        vs[0]+=q0; vq[0]=fmaf(q0,q0,vq[0]);
        vs[1]+=q1; vq[1]=fmaf(q1,q1,vq[1]);
        vs[2]+=q2; vq[2]=fmaf(q2,q2,vq[2]);
        vs[3]+=q3; vq[3]=fmaf(q3,q3,vq[3]);
    }

    const bool l0 = (lane==0), l1 = (lane==1), l62 = (lane==62), l63 = (lane==63);
    float acc = 0.f;

    #pragma unroll
    for (int i = 0; i < ROWS; ++i) {
        const int p = i & 1;
        const int y = y0 + i;

        // ---- export this row's boundary sums ----
        if (halfu == 0) {
            if (l63) {
                *(float4*)&halo[p][0][0] = make_float4(vs[0],vs[1],vs[2],vs[3]);
                *(float4*)&halo[p][0][4] = make_float4(vq[0],vq[1],vq[2],vq[3]);
            }
            if (l62) { halo[p][0][8] = vs[3]; halo[p][0][9] = vq[3]; }
        } else {
            if (l0) {
                *(float4*)&halo[p][1][0] = make_float4(vs[0],vs[1],vs[2],vs[3]);
                *(float4*)&halo[p][1][4] = make_float4(vq[0],vq[1],vq[2],vq[3]);
            }
            if (l1) { halo[p][1][8] = vs[0]; halo[p][1][9] = vq[0]; }
        }
        __syncthreads();

        // this row's global loads (issued immediately after the barrier)
        float4 pv  = *(const float4*)(P + y*HW + c0);
        float4 vn4 = *(const float4*)(T + min(y + PADR + 1, HW-1)*HW + c0);

        // neighbor halo (LDS broadcast reads)
        const int src = halfu ^ 1;
        float4 hs = *(const float4*)&halo[p][src][0];
        float4 hq = *(const float4*)&halo[p][src][4];
        float  hs8 = halo[p][src][8];
        float  hq8 = halo[p][src][9];

        // ---- cross-lane window assembly via DPP ----
        float s_m1_0 = dpp_up1(vs[0]), s_m1_1 = dpp_up1(vs[1]),
              s_m1_2 = dpp_up1(vs[2]), s_m1_3 = dpp_up1(vs[3]);
        float s_m2_3 = dpp_up1(s_m1_3);
        float s_n1_0 = dpp_dn1(vs[0]), s_n1_1 = dpp_dn1(vs[1]),
              s_n1_2 = dpp_dn1(vs[2]), s_n1_3 = dpp_dn1(vs[3]);
        float s_n2_0 = dpp_dn1(s_n1_0);
        float q_m1_0 = dpp_up1(vq[0]), q_m1_1 = dpp_up1(vq[1]),
              q_m1_2 = dpp_up1(vq[2]), q_m1_3 = dpp_up1(vq[3]);
        float q_m2_3 = dpp_up1(q_m1_3);
        float q_n1_0 = dpp_dn1(vq[0]), q_n1_1 = dpp_dn1(vq[1]),
              q_n1_2 = dpp_dn1(vq[2]), q_n1_3 = dpp_dn1(vq[3]);
        float q_n2_0 = dpp_dn1(q_n1_0);

        if (halfu == 0) {            // wave-uniform branch (scalar)
            // left = image edge: replicate col 0
            if (l0) { s_m1_0=vs[0]; s_m1_1=vs[0]; s_m1_2=vs[0]; s_m1_3=vs[0]; s_m2_3=vs[0];
                      q_m1_0=vq[0]; q_m1_1=vq[0]; q_m1_2=vq[0]; q_m1_3=vq[0]; q_m2_3=vq[0]; }
            if (l1) { s_m2_3 = s_m1_0; q_m2_3 = q_m1_0; }
            // right = cross-wave: cols 256-260
            if (l63) { s_n1_0=hs.x; s_n1_1=hs.y; s_n1_2=hs.z; s_n1_3=hs.w; s_n2_0=hs8;
                       q_n1_0=hq.x; q_n1_1=hq.y; q_n1_2=hq.z; q_n1_3=hq.w; q_n2_0=hq8; }
            if (l62) { s_n2_0 = hs.x; q_n2_0 = hq.x; }
        } else {
            // left = cross-wave: cols 251-255 (buf 0-3 = 252-255, buf8 = 251)
            if (l0) { s_m1_0=hs.x; s_m1_1=hs.y; s_m1_2=hs.z; s_m1_3=hs.w; s_m2_3=hs8;
                      q_m1_0=hq.x; q_m1_1=hq.y; q_m1_2=hq.z; q_m1_3=hq.w; q_m2_3=hq8; }
            if (l1) { s_m2_3 = hs.w; q_m2_3 = hq.w; }     // col 255
            // right = image edge: replicate col 511
            if (l63) { s_n1_0=vs[3]; s_n1_1=vs[3]; s_n1_2=vs[3]; s_n1_3=vs[3]; s_n2_0=vs[3];
                       q_n1_0=vq[3]; q_n1_1=vq[3]; q_n1_2=vq[3]; q_n1_3=vq[3]; q_n2_0=vq[3]; }
            if (l62) { s_n2_0 = s_n1_3; q_n2_0 = q_n1_3; }
        }

        // center row (quantized) for the |p - t| term
        h2 clo = fifo[(i+5) % 11][0], chi = fifo[(i+5) % 11][1];
        float tv0=(float)clo.x, tv1=(float)clo.y, tv2=(float)chi.x, tv3=(float)chi.y;

        // sliding 11-box over ext window [c0-5 .. c0+8]
        float bs = s_m2_3 + s_m1_0 + s_m1_1 + s_m1_2 + s_m1_3
                 + vs[0] + vs[1] + vs[2] + vs[3] + s_n1_0 + s_n1_1;
        float bq = q_m2_3 + q_m1_0 + q_m1_1 + q_m1_2 + q_m1_3
                 + vq[0] + vq[1] + vq[2] + vq[3] + q_n1_0 + q_n1_1;

#define EMIT(PV, TV) do { \
            float u = bs * (5.0f/121.0f); \
            float t = fmaf(bq, 25.0f/121.0f, -u*u); \
            t = fminf(fmaxf(t, 0.0f), 4.0f); \
            float w = 1.0f + __builtin_amdgcn_sqrtf(t); \
            acc = fmaf(fabsf((PV) - (TV)), w, acc); \
        } while (0)

        EMIT(pv.x, tv0);
        bs += s_n1_2 - s_m2_3;  bq += q_n1_2 - q_m2_3;  EMIT(pv.y, tv1);
        bs += s_n1_3 - s_m1_0;  bq += q_n1_3 - q_m1_0;  EMIT(pv.z, tv2);
        bs += s_n2_0 - s_m1_1;  bq += q_n2_0 - q_m1_1;  EMIT(pv.w, tv3);
#undef EMIT

        // slide: insert quantized row y+6, remove fifo slot (row y-5)
        {
            h2 nlo, nhi;
            nlo.x=(_Float16)vn4.x; nlo.y=(_Float16)vn4.y;
            nhi.x=(_Float16)vn4.z; nhi.y=(_Float16)vn4.w;
            h2 olo = fifo[i % 11][0], ohi = fifo[i % 11][1];
            float n0=(float)nlo.x, n1=(float)nlo.y, n2=(float)nhi.x, n3=(float)nhi.y;
            float o0=(float)olo.x, o1=(float)olo.y, o2=(float)ohi.x, o3=(float)ohi.y;
            float d0=n0-o0, d1=n1-o1, d2=n2-o2, d3=n3-o3;
            vs[0]+=d0; vq[0]=fmaf(d0, n0+o0, vq[0]);
            vs[1]+=d1; vq[1]=fmaf(d1, n1+o1, vq[1]);
            vs[2]+=d2; vq[2]=fmaf(d2, n2+o2, vq[2]);
            vs[3]+=d3; vq[3]=fmaf(d3, n3+o3, vq[3]);
            fifo[i % 11][0]=nlo; fifo[i % 11][1]=nhi;
        }
    }

    // wave reduce + block reduce
    #pragma unroll
    for (int off = 32; off > 0; off >>= 1)
        acc += __shfl_down(acc, off, 64);
    if (lane == 0) wsum[halfu] = acc;
    __syncthreads();
    if (tid == 0) atomicAdd(out, (wsum[0] + wsum[1]) * invN);
}

extern "C" void kernel_launch(void* const* d_in, const int* in_sizes, int n_in,
                              void* d_out, int out_size, void* d_ws, size_t ws_size,
                              hipStream_t stream) {
    const float* pred = (const float*)d_in[0];
    const float* targ = (const float*)d_in[1];
    float* out = (float*)d_out;

    const int nimg = in_sizes[1] / (HW * HW);       // 96 for (32,3,512,512)
    const float invN = 1.0f / (float)in_sizes[1];

    (void)hipMemsetAsync(out, 0, sizeof(float), stream);  // capture-legal memset node

    const int nblocks = nimg * SEGS;                // 3072 blocks = 6144 waves
    std_loss_kernel<<<nblocks, 128, 0, stream>>>(pred, targ, out, invN);
}

// Round 12
// 49.871 us; speedup vs baseline: 3.8650x; 3.8650x over previous
//
#include <hip/hip_runtime.h>

#define HW 512
#define PADR 5
#define SEGS 32          // segments per image (ROWS = 16)
#define ROWS 16
#define WPB 4            // adjacent segments per block -> halo reuse in L2/L3
#define NXCD 8

typedef _Float16 h2 __attribute__((ext_vector_type(2)));

__device__ __forceinline__ void load8(const float* __restrict__ p, float v[8]) {
    float4 a = *(const float4*)p;
    float4 b = *(const float4*)(p + 4);
    v[0]=a.x; v[1]=a.y; v[2]=a.z; v[3]=a.w;
    v[4]=b.x; v[5]=b.y; v[6]=b.z; v[7]=b.w;
}

// DPP wave shifts: pure VALU, no DS pipe. bound_ctrl=true zeros invalid lanes;
// callers override lane 0 / lane 63 with selects (replicate padding).
__device__ __forceinline__ float dpp_up1(float x) {   // lane i <- lane i-1
    return __int_as_float(__builtin_amdgcn_update_dpp(
        0, __float_as_int(x), 0x138 /*wave_shr:1*/, 0xf, 0xf, true));
}
__device__ __forceinline__ float dpp_dn1(float x) {   // lane i <- lane i+1
    return __int_as_float(__builtin_amdgcn_update_dpp(
        0, __float_as_int(x), 0x130 /*wave_shl:1*/, 0xf, 0xf, true));
}

__global__ __launch_bounds__(256, 3)
void std_loss_kernel(const float* __restrict__ pred,
                     const float* __restrict__ targ,
                     float* __restrict__ out, float invN, int cpx)
{
    const int lane = threadIdx.x & 63;
    const int wib  = threadIdx.x >> 6;

    // XCD-clustered bijective swizzle: hw block b runs on XCD b%8 (round-robin
    // dispatch); give XCD x a contiguous chunk of the work so all 8 blocks of
    // an image (and its halo-sharing neighbors) share one L2. nblocks%8==0.
    const int bid  = (blockIdx.x % NXCD) * cpx + blockIdx.x / NXCD;

    const int wid  = bid * WPB + wib;
    const int img  = wid / SEGS;
    const int seg  = wid - img * SEGS;

    const float* T = targ + (size_t)img * (HW*HW);
    const float* P = pred + (size_t)img * (HW*HW);

    const int c0 = lane * 8;                 // wave covers the full 512-col row
    const int y0 = seg * ROWS;
    const bool l0  = (lane == 0);
    const bool l63 = (lane == 63);

    // ---- 11-row fp16-packed register FIFO: fifo[j] = quantized T[clamp(y0-5+j)] ----
    h2 fifo[11][4];
    float vs[8], vq[8];
    #pragma unroll
    for (int c = 0; c < 8; ++c) { vs[c] = 0.f; vq[c] = 0.f; }
    #pragma unroll
    for (int j = 0; j < 11; ++j) {
        int ry = min(max(y0 - PADR + j, 0), HW - 1);
        float t[8];
        load8(T + ry*HW + c0, t);
        #pragma unroll
        for (int c = 0; c < 4; ++c) {
            h2 v; v.x = (_Float16)t[2*c]; v.y = (_Float16)t[2*c+1];
            fifo[j][c] = v;
            float q0 = (float)v.x, q1 = (float)v.y;
            vs[2*c]   += q0; vq[2*c]   = fmaf(q0, q0, vq[2*c]);
            vs[2*c+1] += q1; vq[2*c+1] = fmaf(q1, q1, vq[2*c+1]);
        }
    }

    // ---- explicit 2-deep A/B prefetch pipeline for the two HBM streams ----
    float vnbuf[2][8], pvbuf[2][8];
    load8(T + min(y0 + 0 + PADR + 1, HW-1)*HW + c0, vnbuf[0]);
    load8(P + (y0 + 0)*HW + c0, pvbuf[0]);
    load8(T + min(y0 + 1 + PADR + 1, HW-1)*HW + c0, vnbuf[1]);
    load8(P + (y0 + 1)*HW + c0, pvbuf[1]);

    float acc = 0.f;

    #pragma unroll
    for (int i = 0; i < ROWS; ++i) {
        const int cur = i & 1;               // compile-time after full unroll

        // cross-lane halo via DPP: prev lane's vs[3..7], next lane's vs[0..4]
        float ups[5], upq[5], dns[5], dnq[5];
        #pragma unroll
        for (int k = 0; k < 5; ++k) {
            float a = dpp_up1(vs[3+k]);
            float b = dpp_up1(vq[3+k]);
            float c = dpp_dn1(vs[k]);
            float d = dpp_dn1(vq[k]);
            ups[k] = l0  ? vs[0] : a;
            upq[k] = l0  ? vq[0] : b;
            dns[k] = l63 ? vs[7] : c;
            dnq[k] = l63 ? vq[7] : d;
        }

        float bs = ups[0]+ups[1]+ups[2]+ups[3]+ups[4]
                 + vs[0]+vs[1]+vs[2]+vs[3]+vs[4]+vs[5];
        float bq = upq[0]+upq[1]+upq[2]+upq[3]+upq[4]
                 + vq[0]+vq[1]+vq[2]+vq[3]+vq[4]+vq[5];

        // center row (quantized) for the |p - t| term
        float tvq[8];
        #pragma unroll
        for (int c = 0; c < 4; ++c) {
            h2 v = fifo[(i+5) % 11][c];
            tvq[2*c] = (float)v.x; tvq[2*c+1] = (float)v.y;
        }

        // w = 1 + sqrt(clamp(25*var, 0, 4));  25*var = bq*25/121 - (bs*5/121)^2
#define EMIT(C) do { \
            float u = bs * (5.0f/121.0f); \
            float t = fmaf(bq, 25.0f/121.0f, -u*u); \
            t = fminf(fmaxf(t, 0.0f), 4.0f); \
            float w = 1.0f + __builtin_amdgcn_sqrtf(t); \
            acc = fmaf(fabsf(pvbuf[cur][C] - tvq[C]), w, acc); \
        } while (0)

        EMIT(0);
        bs += vs[6]  - ups[0];  bq += vq[6]  - upq[0];  EMIT(1);
        bs += vs[7]  - ups[1];  bq += vq[7]  - upq[1];  EMIT(2);
        bs += dns[0] - ups[2];  bq += dnq[0] - upq[2];  EMIT(3);
        bs += dns[1] - ups[3];  bq += dnq[1] - upq[3];  EMIT(4);
        bs += dns[2] - ups[4];  bq += dnq[2] - upq[4];  EMIT(5);
        bs += dns[3] - vs[0];   bq += dnq[3] - vq[0];   EMIT(6);
        bs += dns[4] - vs[1];   bq += dnq[4] - vq[1];   EMIT(7);
#undef EMIT

        // slide window: quantize incoming row, +quantized(y+6), -fifo slot (y-5)
        #pragma unroll
        for (int c = 0; c < 4; ++c) {
            h2 nv; nv.x = (_Float16)vnbuf[cur][2*c]; nv.y = (_Float16)vnbuf[cur][2*c+1];
            h2 ov = fifo[i % 11][c];
            float n0 = (float)nv.x, n1 = (float)nv.y;
            float o0 = (float)ov.x, o1 = (float)ov.y;
            float d0 = n0 - o0, d1 = n1 - o1;
            vs[2*c]   += d0;  vq[2*c]   = fmaf(d0, n0 + o0, vq[2*c]);
            vs[2*c+1] += d1;  vq[2*c+1] = fmaf(d1, n1 + o1, vq[2*c+1]);
            fifo[i % 11][c] = nv;
        }

        // buffer `cur` is free: issue iter i+2's loads (in flight across iter i+1)
        if (i + 2 < ROWS) {
            load8(T + min(y0 + (i+2) + PADR + 1, HW-1)*HW + c0, vnbuf[cur]);
            load8(P + (y0 + (i+2))*HW + c0, pvbuf[cur]);
        }
    }

    // wave reduce
    #pragma unroll
    for (int off = 32; off > 0; off >>= 1)
        acc += __shfl_down(acc, off, 64);

    __shared__ float wsum[WPB];
    if (lane == 0) wsum[wib] = acc;
    __syncthreads();
    if (threadIdx.x == 0) {
        float s = 0.f;
        #pragma unroll
        for (int i = 0; i < WPB; ++i) s += wsum[i];
        atomicAdd(out, s * invN);
    }
}

extern "C" void kernel_launch(void* const* d_in, const int* in_sizes, int n_in,
                              void* d_out, int out_size, void* d_ws, size_t ws_size,
                              hipStream_t stream) {
    const float* pred = (const float*)d_in[0];
    const float* targ = (const float*)d_in[1];
    float* out = (float*)d_out;

    const int nimg = in_sizes[1] / (HW * HW);       // 96 for (32,3,512,512)
    const float invN = 1.0f / (float)in_sizes[1];

    (void)hipMemsetAsync(out, 0, sizeof(float), stream);  // capture-legal memset node

    const int nblocks = nimg * SEGS / WPB;          // 768 (divisible by 8)
    const int cpx = nblocks / NXCD;                 // 96 blocks per XCD chunk
    std_loss_kernel<<<nblocks, 256, 0, stream>>>(pred, targ, out, invN, cpx);
}